// Round 13
// baseline (227.634 us; speedup 1.0000x reference)
//
#include <hip/hip_runtime.h>
#include <hip/hip_bf16.h>

// Problem constants (from reference): B=2, S=2048 -> T=4096 tokens
#define T_TOK 4096
#define DDIM  1024
#define FDIM  512
#define NEXP  16
#define NE17  17       // 16 experts + shared expert as expert 16 (cw=1)
#define MAXTILES 304   // 272 max expert row-tiles + 32 shared; 304 = 8*38 (XCD-exact)
#define MAXROWS  40960 // padded assignment rows (<=34800) + 4096 shared

using bf16x8 = __attribute__((ext_vector_type(8))) __bf16;
using f32x4  = __attribute__((ext_vector_type(4))) float;
using f16x4  = __attribute__((ext_vector_type(4))) _Float16;

// ---------------------------------------------------------------------------
__device__ __forceinline__ void gload_lds16(const void* g, void* l) {
  __builtin_amdgcn_global_load_lds(
      (const __attribute__((address_space(1))) void*)g,
      (__attribute__((address_space(3))) void*)l, 16, 0, 0);
}

// XOR-swizzled ds_read_b128 of one MFMA fragment (8 bf16 along K).
__device__ __forceinline__ bf16x8 frag_ld(const __hip_bfloat16* smem, int row, int chunk) {
  const char* p = (const char*)smem + row * 128 + ((chunk ^ (row & 7)) << 4);
  return *(const bf16x8*)p;
}

// ---------------------------------------------------------------------------
// Fused PREP kernel: grid (8,16,42).
//  z in [0,17):   transpose-convert gate+up pair ([D][F]->[F][D])
//  z in [17,34):  transpose-convert down        ([F][D]->[D][F])
//  z in [34,42):  x->bf16 convert + router (4 tokens/block, 1/wave)
__global__ __launch_bounds__(256, 4) void moe_prep(
    const float* __restrict__ gwM, const float* __restrict__ sgS,
    const float* __restrict__ uwM, const float* __restrict__ suS,
    const float* __restrict__ dwM, const float* __restrict__ sdS,
    __hip_bfloat16* __restrict__ wg, __hip_bfloat16* __restrict__ wu,
    __hip_bfloat16* __restrict__ wd,
    const float* __restrict__ x, const float* __restrict__ rw,
    __hip_bfloat16* __restrict__ xb, float* __restrict__ cwT,
    unsigned* __restrict__ selMask) {
  __shared__ float tA[64][68];   // stride 272B: 16B-aligned rows
  __shared__ float tB[64][68];
  const int z = blockIdx.z;
  const int tid = threadIdx.x;

  if (z >= 2 * NE17) {  // ---- router branch ----
    const int lane = tid & 63;
    const int t = (((z - 2 * NE17) * 128 + blockIdx.y * 8 + blockIdx.x) << 2) + (tid >> 6);
    const float4* xrow = (const float4*)(x + (size_t)t * DDIM);
    float4 v[4];
#pragma unroll
    for (int c = 0; c < 4; c++) v[c] = xrow[lane + 64 * c];
    __hip_bfloat16* orow = xb + (size_t)t * DDIM;
#pragma unroll
    for (int c = 0; c < 4; c++) {
      __hip_bfloat16 h[4] = {__float2bfloat16(v[c].x), __float2bfloat16(v[c].y),
                             __float2bfloat16(v[c].z), __float2bfloat16(v[c].w)};
      *(uint2*)(orow + (lane + 64 * c) * 4) = *(const uint2*)h;
    }
    const float4* rw4 = (const float4*)rw;
    float myLg = 0.f;
#pragma unroll
    for (int e = 0; e < NEXP; e++) {
      float p = 0.f;
#pragma unroll
      for (int c = 0; c < 4; c++) {
        const float4 r = rw4[e * 256 + lane + 64 * c];
        p += v[c].x * r.x + v[c].y * r.y + v[c].z * r.z + v[c].w * r.w;
      }
#pragma unroll
      for (int off = 32; off > 0; off >>= 1) p += __shfl_xor(p, off);
      if (lane == e) myLg = p;
    }
    float m = myLg;
#pragma unroll
    for (int off = 8; off > 0; off >>= 1) m = fmaxf(m, __shfl_xor(m, off));
    const float pe = __expf(myLg - m);
    int rank = 0;
#pragma unroll
    for (int j = 0; j < NEXP; j++) {
      const float pj = __shfl(pe, j);
      rank += ((pj > pe) || (pj == pe && j < lane)) ? 1 : 0;
    }
    const bool sel = (lane < NEXP) && (rank < 8);
    const unsigned mask = (unsigned)(__ballot(sel) & 0xFFFFull);
    float ss = sel ? pe : 0.f;
#pragma unroll
    for (int off = 8; off > 0; off >>= 1) ss += __shfl_xor(ss, off);
    if (lane < NEXP) cwT[(size_t)lane * T_TOK + t] = sel ? pe / ss : 0.f;
    if (lane == 0) selMask[t] = mask;
    return;
  }

  const int lr = tid >> 4, lc = (tid & 15) * 4;
  const int wcc = tid >> 3, seg = (tid & 7) * 8;
  if (z < NE17) {  // ---- gate + up transpose: R=DDIM rows, C=FDIM cols ----
    const int e = z;
    const int R = DDIM, C = FDIM;
    const float* srcA = (e < NEXP) ? gwM + (size_t)e * R * C : sgS;
    const float* srcB = (e < NEXP) ? uwM + (size_t)e * R * C : suS;
    __hip_bfloat16* outA = wg + (size_t)e * R * C;
    __hip_bfloat16* outB = wu + (size_t)e * R * C;
    const int c0 = blockIdx.x * 64, r0 = blockIdx.y * 64;  // x<8, y<16
#pragma unroll
    for (int p = 0; p < 4; p++) {
      const int r = p * 16 + lr;
      *(float4*)&tA[r][lc] = *(const float4*)&srcA[(size_t)(r0 + r) * C + c0 + lc];
      *(float4*)&tB[r][lc] = *(const float4*)&srcB[(size_t)(r0 + r) * C + c0 + lc];
    }
    __syncthreads();
#pragma unroll
    for (int q = 0; q < 2; q++) {
      const int cc = q * 32 + wcc;
      __hip_bfloat16 hA[8], hB[8];
#pragma unroll
      for (int j = 0; j < 8; j++) {
        hA[j] = __float2bfloat16(tA[seg + j][cc]);
        hB[j] = __float2bfloat16(tB[seg + j][cc]);
      }
      *(uint4*)&outA[(size_t)(c0 + cc) * R + r0 + seg] = *(const uint4*)hA;
      *(uint4*)&outB[(size_t)(c0 + cc) * R + r0 + seg] = *(const uint4*)hB;
    }
  } else {  // ---- down transpose: R=FDIM rows, C=DDIM cols ----
    const int e = z - NE17;
    const int R = FDIM, C = DDIM;
    const float* src = (e < NEXP) ? dwM + (size_t)e * R * C : sdS;
    __hip_bfloat16* out = wd + (size_t)e * R * C;
    const int id = blockIdx.y * 8 + blockIdx.x;  // 0..127
    const int c0 = (id & 15) * 64, r0 = (id >> 4) * 64;
#pragma unroll
    for (int p = 0; p < 4; p++) {
      const int r = p * 16 + lr;
      *(float4*)&tA[r][lc] = *(const float4*)&src[(size_t)(r0 + r) * C + c0 + lc];
    }
    __syncthreads();
#pragma unroll
    for (int q = 0; q < 2; q++) {
      const int cc = q * 32 + wcc;
      __hip_bfloat16 h[8];
#pragma unroll
      for (int j = 0; j < 8; j++) h[j] = __float2bfloat16(tA[seg + j][cc]);
      *(uint4*)&out[(size_t)(c0 + cc) * R + r0 + seg] = *(const uint4*)h;
    }
  }
}

// ---------------------------------------------------------------------------
// Grouping: 17 blocks x 256 threads (4 waves). Wave w counts+places the w-th
// quarter of tokens; per-quarter counts via LDS give each wave its offset.
__global__ __launch_bounds__(256) void moe_group(
    const float* __restrict__ cwT, const unsigned* __restrict__ selMask,
    int* __restrict__ padBase, int* __restrict__ tileE, int* __restrict__ tileBase,
    int* __restrict__ perm, float* __restrict__ rowW, int* __restrict__ tok2row) {
  __shared__ int cq[4][NEXP];
  const int e = blockIdx.x;  // 0..16
  const int tid = threadIdx.x;
  const int wid = tid >> 6, lane = tid & 63;
  const int tq = wid * (T_TOK / 4);
  int c[NEXP];
#pragma unroll
  for (int i = 0; i < NEXP; i++) c[i] = 0;
  for (int it = 0; it < T_TOK / 4 / 64; it++) {
    const unsigned sm = selMask[tq + it * 64 + lane];
#pragma unroll
    for (int i = 0; i < NEXP; i++) c[i] += (sm >> i) & 1;
  }
#pragma unroll
  for (int i = 0; i < NEXP; i++) {
#pragma unroll
    for (int off = 32; off > 0; off >>= 1) c[i] += __shfl_xor(c[i], off);
  }
  if (lane < NEXP) cq[wid][lane] = c[lane];
  __syncthreads();
  int cf[NEXP], pb[NE17];
  int base = 0;
#pragma unroll
  for (int i = 0; i < NEXP; i++) {
    cf[i] = cq[0][i] + cq[1][i] + cq[2][i] + cq[3][i];
    pb[i] = base;
    base += ((cf[i] + 127) >> 7) << 7;
  }
  pb[16] = base;

  if (e == 16) {
    if (tid < NE17) padBase[tid] = pb[tid];
    int totTiles = 32;
#pragma unroll
    for (int i = 0; i < NEXP; i++) totTiles += (cf[i] + 127) >> 7;
    if (tid < NEXP) {
      int slot = 0;
      for (int j = 0; j < tid; j++) slot += (cf[j] + 127) >> 7;
      const int nt = (cf[tid] + 127) >> 7;
      for (int k = 0; k < nt; k++) {
        tileE[slot + k] = tid; tileBase[slot + k] = pb[tid] + (k << 7);
      }
    } else if (tid == NEXP) {
      int slot = 0;
      for (int j = 0; j < NEXP; j++) slot += (cf[j] + 127) >> 7;
      for (int k = 0; k < 32; k++) {
        tileE[slot + k] = 16; tileBase[slot + k] = pb[16] + (k << 7);
      }
    }
    for (int idx = tid; idx < MAXTILES; idx += 256)
      if (idx >= totTiles) tileE[idx] = -1;
    for (int t = tid; t < T_TOK; t += 256) {
      perm[pb[16] + t] = t; rowW[pb[16] + t] = 1.0f;
    }
    return;
  }
  int running = 0;
  for (int w = 0; w < 4; w++) if (w < wid) running += cq[w][e];
  const int myBase = pb[e];
  for (int it = 0; it < T_TOK / 4 / 64; it++) {
    const int t = tq + it * 64 + lane;
    const unsigned sm = selMask[t];
    const bool selE = (sm >> e) & 1;
    const unsigned long long m = __ballot(selE);
    if (selE) {
      const int r = myBase + running + __popcll(m & ((1ull << lane) - 1ull));
      perm[r] = t; rowW[r] = cwT[(size_t)e * T_TOK + t];
      tok2row[t * 8 + __popc(sm & ((1u << e) - 1u))] = r;
    }
    running += __popcll(m);
  }
  const int padded = ((cf[e] + 127) >> 7) << 7;
  for (int i = cf[e] + tid; i < padded; i += 256) {
    perm[myBase + i] = -1; rowW[myBase + i] = 0.f;
  }
}

// ---------------------------------------------------------------------------
// Stage A (grouped/sparse, f-width 64). LDS exactly 32 KB (no sTok/sW arrays;
// perm/rowW read from global, L1-hot) -> 5 blocks/CU at RUNTIME while the
// launch bound stays 4 (reg cap 128; compiler uses ~64 -> no spill).
__global__ __launch_bounds__(256, 4) void moe_stageA_grouped(
    const __hip_bfloat16* __restrict__ xb,   // [T][D]
    const __hip_bfloat16* __restrict__ wg,   // [17][F][D]
    const __hip_bfloat16* __restrict__ wu,   // [17][F][D]
    const int* __restrict__ perm, const float* __restrict__ rowW,
    const int* __restrict__ tileE, const int* __restrict__ tileBase,
    __hip_bfloat16* __restrict__ H, int groupedStore)
{
  __shared__ __hip_bfloat16 sA[128 * 64];   // 16 KB
  __shared__ __hip_bfloat16 sG[64 * 64];    // 8 KB
  __shared__ __hip_bfloat16 sU[64 * 64];    // 8 KB   -> exactly 32 KB total

  const int tile = (blockIdx.x & 7) * (MAXTILES / 8) + (blockIdx.x >> 3);
  const int e = tileE[tile];
  if (e < 0) return;
  const int rbase = tileBase[tile];
  const int f0 = blockIdx.y * 64;
  const int tid = threadIdx.x;
  const int wid = tid >> 6, lane = tid & 63;
  const int wr = (wid >> 1) * 64, wc = (wid & 1) * 32;  // wave tile 64x32 (dual)
  const int rl = lane >> 3, cl = lane & 7;

  const __hip_bfloat16* wgE = wg + (size_t)e * FDIM * DDIM;
  const __hip_bfloat16* wuE = wu + (size_t)e * FDIM * DDIM;

  const char* pA[4]; const char* pG[2]; const char* pU[2]; int ldsA[4], ldsB[2];
#pragma unroll
  for (int i = 0; i < 4; i++) {
    const int row = 32 * wid + 8 * i + rl;
    const int sw = (cl ^ (row & 7)) << 3;
    int tk = perm[rbase + row]; if (tk < 0) tk = 0;
    pA[i] = (const char*)(xb + (size_t)tk * DDIM + sw);
    ldsA[i] = (32 * wid + 8 * i) * 64;
  }
#pragma unroll
  for (int i = 0; i < 2; i++) {
    const int row = 16 * wid + 8 * i + rl;
    const int sw = (cl ^ (row & 7)) << 3;
    pG[i] = (const char*)(wgE + (size_t)(f0 + row) * DDIM + sw);
    pU[i] = (const char*)(wuE + (size_t)(f0 + row) * DDIM + sw);
    ldsB[i] = (16 * wid + 8 * i) * 64;
  }

  const f32x4 vzero = {0.f, 0.f, 0.f, 0.f};
  f32x4 accG[4][2], accU[4][2];
#pragma unroll
  for (int m = 0; m < 4; m++)
#pragma unroll
    for (int n = 0; n < 2; n++) { accG[m][n] = vzero; accU[m][n] = vzero; }

  for (int k0 = 0; k0 < DDIM; k0 += 64) {
    __syncthreads();
#pragma unroll
    for (int i = 0; i < 4; i++) gload_lds16(pA[i] + (size_t)k0 * 2, &sA[ldsA[i]]);
#pragma unroll
    for (int i = 0; i < 2; i++) {
      gload_lds16(pG[i] + (size_t)k0 * 2, &sG[ldsB[i]]);
      gload_lds16(pU[i] + (size_t)k0 * 2, &sU[ldsB[i]]);
    }
    __syncthreads();
#pragma unroll
    for (int kk = 0; kk < 2; kk++) {
      const int kch = kk * 4 + (lane >> 4);
      bf16x8 af[4], bg[2], bu[2];
#pragma unroll
      for (int m = 0; m < 4; m++) af[m] = frag_ld(sA, wr + m * 16 + (lane & 15), kch);
#pragma unroll
      for (int n = 0; n < 2; n++) {
        bg[n] = frag_ld(sG, wc + n * 16 + (lane & 15), kch);
        bu[n] = frag_ld(sU, wc + n * 16 + (lane & 15), kch);
      }
#pragma unroll
      for (int m = 0; m < 4; m++)
#pragma unroll
        for (int n = 0; n < 2; n++) {
          accG[m][n] = __builtin_amdgcn_mfma_f32_16x16x32_bf16(af[m], bg[n], accG[m][n], 0, 0, 0);
          accU[m][n] = __builtin_amdgcn_mfma_f32_16x16x32_bf16(af[m], bu[n], accU[m][n], 0, 0, 0);
        }
    }
  }
  const int lr = (lane >> 4) * 4, lc = lane & 15;
#pragma unroll
  for (int m = 0; m < 4; m++)
#pragma unroll
    for (int j = 0; j < 4; j++) {
      const int r = wr + m * 16 + lr + j;
      const int tok = perm[rbase + r];
      if (tok < 0) continue;
      const float w = rowW[rbase + r];
#pragma unroll
      for (int n = 0; n < 2; n++) {
        const int c = wc + n * 16 + lc;
        const float g = accG[m][n][j], u = accU[m][n][j];
        const float h = (g / (1.0f + __expf(-g))) * u * w;
        const size_t idx = groupedStore
            ? ((size_t)(rbase + r) * FDIM + f0 + c)
            : (((size_t)e * T_TOK + tok) * FDIM + f0 + c);
        H[idx] = __float2bfloat16(h);
      }
    }
}

// ---------------------------------------------------------------------------
// Stage B grouped: outp[row][d] = Hp[row][:] @ wd_t[e][d][:] (K=512), fp16 out.
// LDS exactly 32 KB, VGPR 88 (<=102) -> up to 5 blocks/CU at runtime.
__global__ __launch_bounds__(256, 4) void moe_stageB_grouped(
    const __hip_bfloat16* __restrict__ Hp,   // [MAXROWS][F]
    const __hip_bfloat16* __restrict__ wd,   // [17][D][F]
    const int* __restrict__ tileE, const int* __restrict__ tileBase,
    _Float16* __restrict__ outp)             // [MAXROWS][D] fp16
{
  __shared__ __hip_bfloat16 sA[128 * 64];
  __shared__ __hip_bfloat16 sB[128 * 64];

  const int tile = (blockIdx.x & 7) * (MAXTILES / 8) + (blockIdx.x >> 3);
  const int e = tileE[tile];
  if (e < 0) return;
  const int rbase = tileBase[tile];
  const int d0 = blockIdx.y * 128;
  const int tid = threadIdx.x, wid = tid >> 6, lane = tid & 63;
  const int wr = (wid >> 1) * 64, wc = (wid & 1) * 64;  // wave tile 64x64
  const int rl = lane >> 3, cl = lane & 7;

  const __hip_bfloat16* wdE = wd + (size_t)e * DDIM * FDIM;

  size_t offA[4], offB[4]; int ldsO[4];
#pragma unroll
  for (int i = 0; i < 4; i++) {
    const int row = 32 * wid + 8 * i + rl;
    const int sw = (cl ^ (row & 7)) << 3;
    offA[i] = (size_t)(rbase + row) * FDIM + sw;
    offB[i] = (size_t)(d0 + row) * FDIM + sw;
    ldsO[i] = (32 * wid + 8 * i) * 64;
  }

  const f32x4 vzero = {0.f, 0.f, 0.f, 0.f};
  f32x4 acc[4][4];
#pragma unroll
  for (int m = 0; m < 4; m++)
#pragma unroll
    for (int n = 0; n < 4; n++) acc[m][n] = vzero;

  for (int k0 = 0; k0 < FDIM; k0 += 64) {
    __syncthreads();
#pragma unroll
    for (int i = 0; i < 4; i++) {
      gload_lds16(Hp  + offA[i] + k0, &sA[ldsO[i]]);
      gload_lds16(wdE + offB[i] + k0, &sB[ldsO[i]]);
    }
    __syncthreads();
#pragma unroll
    for (int kk = 0; kk < 2; kk++) {
      const int kch = kk * 4 + (lane >> 4);
      bf16x8 af[4], bb[4];
#pragma unroll
      for (int m = 0; m < 4; m++) af[m] = frag_ld(sA, wr + m * 16 + (lane & 15), kch);
#pragma unroll
      for (int n = 0; n < 4; n++) bb[n] = frag_ld(sB, wc + n * 16 + (lane & 15), kch);
#pragma unroll
      for (int m = 0; m < 4; m++)
#pragma unroll
        for (int n = 0; n < 4; n++)
          acc[m][n] = __builtin_amdgcn_mfma_f32_16x16x32_bf16(af[m], bb[n], acc[m][n], 0, 0, 0);
    }
  }
  const int lr = (lane >> 4) * 4, lc = lane & 15;
#pragma unroll
  for (int m = 0; m < 4; m++)
#pragma unroll
    for (int n = 0; n < 4; n++)
#pragma unroll
      for (int j = 0; j < 4; j++)
        outp[(size_t)(rbase + wr + m * 16 + lr + j) * DDIM + d0 + wc + n * 16 + lc]
            = (_Float16)acc[m][n][j];
}

// Combine: out[t] = outp[sharedRow(t)] + sum_{s=0..7} outp[tok2row[t][s]]
__global__ __launch_bounds__(256) void moe_combine(
    const _Float16* __restrict__ outp, const int* __restrict__ tok2row,
    const int* __restrict__ padBase, float* __restrict__ out) {
  const int tid = threadIdx.x;  // 256; 256*f16x4 = 1024 = DDIM
  const int pb16 = padBase[16];
  const int tEnd = blockIdx.x * 8 + 8;
  for (int t = blockIdx.x * 8; t < tEnd; t++) {
    float4 a = {0.f, 0.f, 0.f, 0.f};
    {
      const f16x4 v = ((const f16x4*)(outp + (size_t)(pb16 + t) * DDIM))[tid];
      a.x += (float)v[0]; a.y += (float)v[1]; a.z += (float)v[2]; a.w += (float)v[3];
    }
#pragma unroll
    for (int s = 0; s < 8; s++) {
      const int r = tok2row[t * 8 + s];  // same addr across threads: broadcast
      const f16x4 v = ((const f16x4*)(outp + (size_t)r * DDIM))[tid];
      a.x += (float)v[0]; a.y += (float)v[1]; a.z += (float)v[2]; a.w += (float)v[3];
    }
    ((float4*)out)[(size_t)t * (DDIM / 4) + tid] = a;
  }
}

// ---------------------------------------------------------------------------
// Fallback dense stage B (round-6 path): K-split x3 over concat experts.
__global__ __launch_bounds__(256, 4) void moe_stageB_split(
    const __hip_bfloat16* __restrict__ H,    // [17][T][F] dense
    const __hip_bfloat16* __restrict__ wd,   // [17][D][F]
    float* __restrict__ out, float* __restrict__ p0, float* __restrict__ p1)
{
  __shared__ __hip_bfloat16 sA[128 * 64];
  __shared__ __hip_bfloat16 sB[128 * 64];
  const int id = blockIdx.x;
  const int xcd = id & 7, slot = id >> 3;
  const int t0 = (xcd * 4 + (slot & 3)) * 128;
  const int d0 = (slot >> 2) * 128;
  const int tid = threadIdx.x, wid = tid >> 6, lane = tid & 63;
  const int wr = (wid >> 1) * 64, wc = (wid & 1) * 64;
  const int rl = lane >> 3, cl = lane & 7;
  size_t offA[4], offB[4]; int ldsO[4];
#pragma unroll
  for (int i = 0; i < 4; i++) {
    const int row = 32 * wid + 8 * i + rl;
    const int sw = (cl ^ (row & 7)) << 3;
    offA[i] = (size_t)(t0 + row) * FDIM + sw;
    offB[i] = (size_t)(d0 + row) * FDIM + sw;
    ldsO[i] = (32 * wid + 8 * i) * 64;
  }
  const f32x4 vzero = {0.f, 0.f, 0.f, 0.f};
  f32x4 acc[4][4];
#pragma unroll
  for (int m = 0; m < 4; m++)
#pragma unroll
    for (int n = 0; n < 4; n++) acc[m][n] = vzero;
  const int NKS = NE17 * FDIM / 64;
  const int split = blockIdx.y;
  const int ks0 = (split * NKS) / 3, ks1 = ((split + 1) * NKS) / 3;
  for (int ks = ks0; ks < ks1; ks++) {
    const int k0 = ks * 64;
    const int ee = k0 >> 9, ff = k0 & 511;
    const size_t sOffA = (size_t)ee * T_TOK * FDIM + ff;
    const size_t sOffB = (size_t)ee * DDIM * FDIM + ff;
    __syncthreads();
#pragma unroll
    for (int i = 0; i < 4; i++) {
      gload_lds16(H  + sOffA + offA[i], &sA[ldsO[i]]);
      gload_lds16(wd + sOffB + offB[i], &sB[ldsO[i]]);
    }
    __syncthreads();
#pragma unroll
    for (int kk = 0; kk < 2; kk++) {
      const int kch = kk * 4 + (lane >> 4);
      bf16x8 af[4], bb[4];
#pragma unroll
      for (int m = 0; m < 4; m++) af[m] = frag_ld(sA, wr + m * 16 + (lane & 15), kch);
#pragma unroll
      for (int n = 0; n < 4; n++) bb[n] = frag_ld(sB, wc + n * 16 + (lane & 15), kch);
#pragma unroll
      for (int m = 0; m < 4; m++)
#pragma unroll
        for (int n = 0; n < 4; n++)
          acc[m][n] = __builtin_amdgcn_mfma_f32_16x16x32_bf16(af[m], bb[n], acc[m][n], 0, 0, 0);
    }
  }
  float* dst = (split == 0) ? p0 : (split == 1) ? p1 : out;
  const int lr = (lane >> 4) * 4, lc = lane & 15;
#pragma unroll
  for (int m = 0; m < 4; m++)
#pragma unroll
    for (int n = 0; n < 4; n++)
#pragma unroll
      for (int j = 0; j < 4; j++)
        dst[(size_t)(t0 + wr + m * 16 + lr + j) * DDIM + d0 + wc + n * 16 + lc] = acc[m][n][j];
}

__global__ void add_partial(float* __restrict__ out, const float* __restrict__ p0,
                            const float* __restrict__ p1, int n4) {
  int i = blockIdx.x * blockDim.x + threadIdx.x;
  if (i >= n4) return;
  float4 a = ((const float4*)out)[i];
  float4 b = ((const float4*)p0)[i];
  float4 c = ((const float4*)p1)[i];
  a.x += b.x + c.x; a.y += b.y + c.y; a.z += b.z + c.z; a.w += b.w + c.w;
  ((float4*)out)[i] = a;
}

// ---------------------------------------------------------------------------
extern "C" void kernel_launch(void* const* d_in, const int* in_sizes, int n_in,
                              void* d_out, int out_size, void* d_ws, size_t ws_size,
                              hipStream_t stream) {
  const float* x  = (const float*)d_in[0];
  const float* rw = (const float*)d_in[1];
  const float* gw = (const float*)d_in[2];
  const float* uw = (const float*)d_in[3];
  const float* dw = (const float*)d_in[4];
  const float* sg = (const float*)d_in[5];
  const float* su = (const float*)d_in[6];
  const float* sd = (const float*)d_in[7];
  float* out = (float*)d_out;

  char* ws = (char*)d_ws;
  size_t off = 0;
  __hip_bfloat16* xb = (__hip_bfloat16*)(ws + off); off += (size_t)T_TOK * DDIM * 2;
  __hip_bfloat16* wg = (__hip_bfloat16*)(ws + off); off += (size_t)NE17 * FDIM * DDIM * 2;
  __hip_bfloat16* wu = (__hip_bfloat16*)(ws + off);
  const size_t wu_off = off;                         off += (size_t)NE17 * FDIM * DDIM * 2;
  __hip_bfloat16* wd = (__hip_bfloat16*)(ws + off);  off += (size_t)NE17 * DDIM * FDIM * 2;
  __hip_bfloat16* H  = (__hip_bfloat16*)(ws + off);
  const size_t H_bytes = (size_t)NE17 * T_TOK * FDIM * 2; off += H_bytes;
  float* cwT     = (float*)(ws + off); off += (size_t)NEXP * T_TOK * 4;
  int*   padBase = (int*)(ws + off);   off += 32 * 4;
  int*   tileE   = (int*)(ws + off);   off += MAXTILES * 4;
  int*   tileBase= (int*)(ws + off);   off += MAXTILES * 4;
  int*   perm    = (int*)(ws + off);   off += MAXROWS * 4;
  float* rowW    = (float*)(ws + off); off += MAXROWS * 4;
  unsigned* selMask = (unsigned*)(ws + off); off += (size_t)T_TOK * 4;
  int*   tok2row = (int*)(ws + off);   off += (size_t)T_TOK * 8 * 4;
  // grouped-mode extra: fp16 outp[MAXROWS][D] appended at the end (83.9 MB)
  const size_t outp_bytes = (size_t)MAXROWS * DDIM * 2;
  _Float16* outp = (_Float16*)(ws + off);
  const bool grouped = (ws_size >= off + outp_bytes);
  // fallback partials alias dead regions (xb+wg, wu)
  float* p0 = (float*)ws;
  float* p1 = (float*)(ws + wu_off);
  (void)in_sizes; (void)n_in; (void)out_size;

  if (!grouped) hipMemsetAsync(H, 0, H_bytes, stream);  // dense H needs zeros

  // one prep launch: weight transposes (z<34) + x-convert/router (z>=34)
  moe_prep<<<dim3(8, 16, 2 * NE17 + 8), 256, 0, stream>>>(
      gw, sg, uw, su, dw, sd, wg, wu, wd, x, rw, xb, cwT, selMask);
  moe_group<<<NE17, 256, 0, stream>>>(cwT, selMask, padBase, tileE, tileBase,
                                      perm, rowW, tok2row);

  moe_stageA_grouped<<<dim3(MAXTILES, FDIM / 64), 256, 0, stream>>>(
      xb, wg, wu, perm, rowW, tileE, tileBase, H, grouped ? 1 : 0);

  if (grouped) {
    moe_stageB_grouped<<<dim3(MAXTILES, DDIM / 128), 256, 0, stream>>>(
        H, wd, tileE, tileBase, outp);
    moe_combine<<<T_TOK / 8, 256, 0, stream>>>(outp, tok2row, padBase, out);
  } else {
    moe_stageB_split<<<dim3(256, 3), 256, 0, stream>>>(H, wd, out, p0, p1);
    add_partial<<<(T_TOK * DDIM / 4 + 255) / 256, 256, 0, stream>>>(out, p0, p1, T_TOK * DDIM / 4);
  }
}

// Round 14
// 220.837 us; speedup vs baseline: 1.0308x; 1.0308x over previous
//
#include <hip/hip_runtime.h>
#include <hip/hip_bf16.h>

// Problem constants (from reference): B=2, S=2048 -> T=4096 tokens
#define T_TOK 4096
#define DDIM  1024
#define FDIM  512
#define NEXP  16
#define NE17  17       // 16 experts + shared expert as expert 16 (cw=1)
#define MAXTILES 304   // 272 max expert row-tiles + 32 shared; 304 = 8*38 (XCD-exact)
#define MAXROWS  40960 // padded assignment rows (<=34800) + 4096 shared

using bf16x8 = __attribute__((ext_vector_type(8))) __bf16;
using f32x4  = __attribute__((ext_vector_type(4))) float;
using f16x4  = __attribute__((ext_vector_type(4))) _Float16;

// ---------------------------------------------------------------------------
__device__ __forceinline__ void gload_lds16(const void* g, void* l) {
  __builtin_amdgcn_global_load_lds(
      (const __attribute__((address_space(1))) void*)g,
      (__attribute__((address_space(3))) void*)l, 16, 0, 0);
}

// XOR-swizzled ds_read_b128 of one MFMA fragment (8 bf16 along K).
__device__ __forceinline__ bf16x8 frag_ld(const __hip_bfloat16* smem, int row, int chunk) {
  const char* p = (const char*)smem + row * 128 + ((chunk ^ (row & 7)) << 4);
  return *(const bf16x8*)p;
}

// ---------------------------------------------------------------------------
// Fused PREP kernel: grid (8,16,42).
//  z in [0,17):   transpose-convert gate+up pair ([D][F]->[F][D])
//  z in [17,34):  transpose-convert down        ([F][D]->[D][F])
//  z in [34,42):  x->bf16 convert + router (4 tokens/block, 1/wave)
__global__ __launch_bounds__(256, 4) void moe_prep(
    const float* __restrict__ gwM, const float* __restrict__ sgS,
    const float* __restrict__ uwM, const float* __restrict__ suS,
    const float* __restrict__ dwM, const float* __restrict__ sdS,
    __hip_bfloat16* __restrict__ wg, __hip_bfloat16* __restrict__ wu,
    __hip_bfloat16* __restrict__ wd,
    const float* __restrict__ x, const float* __restrict__ rw,
    __hip_bfloat16* __restrict__ xb, float* __restrict__ cwT,
    unsigned* __restrict__ selMask) {
  __shared__ float tA[64][68];   // stride 272B: 16B-aligned rows
  __shared__ float tB[64][68];
  const int z = blockIdx.z;
  const int tid = threadIdx.x;

  if (z >= 2 * NE17) {  // ---- router branch ----
    const int lane = tid & 63;
    const int t = (((z - 2 * NE17) * 128 + blockIdx.y * 8 + blockIdx.x) << 2) + (tid >> 6);
    const float4* xrow = (const float4*)(x + (size_t)t * DDIM);
    float4 v[4];
#pragma unroll
    for (int c = 0; c < 4; c++) v[c] = xrow[lane + 64 * c];
    __hip_bfloat16* orow = xb + (size_t)t * DDIM;
#pragma unroll
    for (int c = 0; c < 4; c++) {
      __hip_bfloat16 h[4] = {__float2bfloat16(v[c].x), __float2bfloat16(v[c].y),
                             __float2bfloat16(v[c].z), __float2bfloat16(v[c].w)};
      *(uint2*)(orow + (lane + 64 * c) * 4) = *(const uint2*)h;
    }
    const float4* rw4 = (const float4*)rw;
    float myLg = 0.f;
#pragma unroll
    for (int e = 0; e < NEXP; e++) {
      float p = 0.f;
#pragma unroll
      for (int c = 0; c < 4; c++) {
        const float4 r = rw4[e * 256 + lane + 64 * c];
        p += v[c].x * r.x + v[c].y * r.y + v[c].z * r.z + v[c].w * r.w;
      }
#pragma unroll
      for (int off = 32; off > 0; off >>= 1) p += __shfl_xor(p, off);
      if (lane == e) myLg = p;
    }
    float m = myLg;
#pragma unroll
    for (int off = 8; off > 0; off >>= 1) m = fmaxf(m, __shfl_xor(m, off));
    const float pe = __expf(myLg - m);
    int rank = 0;
#pragma unroll
    for (int j = 0; j < NEXP; j++) {
      const float pj = __shfl(pe, j);
      rank += ((pj > pe) || (pj == pe && j < lane)) ? 1 : 0;
    }
    const bool sel = (lane < NEXP) && (rank < 8);
    const unsigned mask = (unsigned)(__ballot(sel) & 0xFFFFull);
    float ss = sel ? pe : 0.f;
#pragma unroll
    for (int off = 8; off > 0; off >>= 1) ss += __shfl_xor(ss, off);
    if (lane < NEXP) cwT[(size_t)lane * T_TOK + t] = sel ? pe / ss : 0.f;
    if (lane == 0) selMask[t] = mask;
    return;
  }

  const int lr = tid >> 4, lc = (tid & 15) * 4;
  const int wcc = tid >> 3, seg = (tid & 7) * 8;
  if (z < NE17) {  // ---- gate + up transpose: R=DDIM rows, C=FDIM cols ----
    const int e = z;
    const int R = DDIM, C = FDIM;
    const float* srcA = (e < NEXP) ? gwM + (size_t)e * R * C : sgS;
    const float* srcB = (e < NEXP) ? uwM + (size_t)e * R * C : suS;
    __hip_bfloat16* outA = wg + (size_t)e * R * C;
    __hip_bfloat16* outB = wu + (size_t)e * R * C;
    const int c0 = blockIdx.x * 64, r0 = blockIdx.y * 64;  // x<8, y<16
#pragma unroll
    for (int p = 0; p < 4; p++) {
      const int r = p * 16 + lr;
      *(float4*)&tA[r][lc] = *(const float4*)&srcA[(size_t)(r0 + r) * C + c0 + lc];
      *(float4*)&tB[r][lc] = *(const float4*)&srcB[(size_t)(r0 + r) * C + c0 + lc];
    }
    __syncthreads();
#pragma unroll
    for (int q = 0; q < 2; q++) {
      const int cc = q * 32 + wcc;
      __hip_bfloat16 hA[8], hB[8];
#pragma unroll
      for (int j = 0; j < 8; j++) {
        hA[j] = __float2bfloat16(tA[seg + j][cc]);
        hB[j] = __float2bfloat16(tB[seg + j][cc]);
      }
      *(uint4*)&outA[(size_t)(c0 + cc) * R + r0 + seg] = *(const uint4*)hA;
      *(uint4*)&outB[(size_t)(c0 + cc) * R + r0 + seg] = *(const uint4*)hB;
    }
  } else {  // ---- down transpose: R=FDIM rows, C=DDIM cols ----
    const int e = z - NE17;
    const int R = FDIM, C = DDIM;
    const float* src = (e < NEXP) ? dwM + (size_t)e * R * C : sdS;
    __hip_bfloat16* out = wd + (size_t)e * R * C;
    const int id = blockIdx.y * 8 + blockIdx.x;  // 0..127
    const int c0 = (id & 15) * 64, r0 = (id >> 4) * 64;
#pragma unroll
    for (int p = 0; p < 4; p++) {
      const int r = p * 16 + lr;
      *(float4*)&tA[r][lc] = *(const float4*)&src[(size_t)(r0 + r) * C + c0 + lc];
    }
    __syncthreads();
#pragma unroll
    for (int q = 0; q < 2; q++) {
      const int cc = q * 32 + wcc;
      __hip_bfloat16 h[8];
#pragma unroll
      for (int j = 0; j < 8; j++) h[j] = __float2bfloat16(tA[seg + j][cc]);
      *(uint4*)&out[(size_t)(c0 + cc) * R + r0 + seg] = *(const uint4*)h;
    }
  }
}

// ---------------------------------------------------------------------------
// Grouping: 17 blocks x 256 threads (4 waves). Wave w counts+places the w-th
// quarter of tokens; per-quarter counts via LDS give each wave its offset.
__global__ __launch_bounds__(256) void moe_group(
    const float* __restrict__ cwT, const unsigned* __restrict__ selMask,
    int* __restrict__ padBase, int* __restrict__ tileE, int* __restrict__ tileBase,
    int* __restrict__ perm, float* __restrict__ rowW, int* __restrict__ tok2row) {
  __shared__ int cq[4][NEXP];
  const int e = blockIdx.x;  // 0..16
  const int tid = threadIdx.x;
  const int wid = tid >> 6, lane = tid & 63;
  const int tq = wid * (T_TOK / 4);
  int c[NEXP];
#pragma unroll
  for (int i = 0; i < NEXP; i++) c[i] = 0;
  for (int it = 0; it < T_TOK / 4 / 64; it++) {
    const unsigned sm = selMask[tq + it * 64 + lane];
#pragma unroll
    for (int i = 0; i < NEXP; i++) c[i] += (sm >> i) & 1;
  }
#pragma unroll
  for (int i = 0; i < NEXP; i++) {
#pragma unroll
    for (int off = 32; off > 0; off >>= 1) c[i] += __shfl_xor(c[i], off);
  }
  if (lane < NEXP) cq[wid][lane] = c[lane];
  __syncthreads();
  int cf[NEXP], pb[NE17];
  int base = 0;
#pragma unroll
  for (int i = 0; i < NEXP; i++) {
    cf[i] = cq[0][i] + cq[1][i] + cq[2][i] + cq[3][i];
    pb[i] = base;
    base += ((cf[i] + 127) >> 7) << 7;
  }
  pb[16] = base;

  if (e == 16) {
    if (tid < NE17) padBase[tid] = pb[tid];
    int totTiles = 32;
#pragma unroll
    for (int i = 0; i < NEXP; i++) totTiles += (cf[i] + 127) >> 7;
    if (tid < NEXP) {
      int slot = 0;
      for (int j = 0; j < tid; j++) slot += (cf[j] + 127) >> 7;
      const int nt = (cf[tid] + 127) >> 7;
      for (int k = 0; k < nt; k++) {
        tileE[slot + k] = tid; tileBase[slot + k] = pb[tid] + (k << 7);
      }
    } else if (tid == NEXP) {
      int slot = 0;
      for (int j = 0; j < NEXP; j++) slot += (cf[j] + 127) >> 7;
      for (int k = 0; k < 32; k++) {
        tileE[slot + k] = 16; tileBase[slot + k] = pb[16] + (k << 7);
      }
    }
    for (int idx = tid; idx < MAXTILES; idx += 256)
      if (idx >= totTiles) tileE[idx] = -1;
    for (int t = tid; t < T_TOK; t += 256) {
      perm[pb[16] + t] = t; rowW[pb[16] + t] = 1.0f;
    }
    return;
  }
  int running = 0;
  for (int w = 0; w < 4; w++) if (w < wid) running += cq[w][e];
  const int myBase = pb[e];
  for (int it = 0; it < T_TOK / 4 / 64; it++) {
    const int t = tq + it * 64 + lane;
    const unsigned sm = selMask[t];
    const bool selE = (sm >> e) & 1;
    const unsigned long long m = __ballot(selE);
    if (selE) {
      const int r = myBase + running + __popcll(m & ((1ull << lane) - 1ull));
      perm[r] = t; rowW[r] = cwT[(size_t)e * T_TOK + t];
      tok2row[t * 8 + __popc(sm & ((1u << e) - 1u))] = r;
    }
    running += __popcll(m);
  }
  const int padded = ((cf[e] + 127) >> 7) << 7;
  for (int i = cf[e] + tid; i < padded; i += 256) {
    perm[myBase + i] = -1; rowW[myBase + i] = 0.f;
  }
}

// ---------------------------------------------------------------------------
// Stage A (grouped/sparse, f-width 64). PROVEN round-10/12 codegen: bounds
// (256,4), VGPR 64, no spill. sTok/sW staged in LDS (faster than global reads
// — round-13 A/B showed -6.5us for the global-read variant).
__global__ __launch_bounds__(256, 4) void moe_stageA_grouped(
    const __hip_bfloat16* __restrict__ xb,   // [T][D]
    const __hip_bfloat16* __restrict__ wg,   // [17][F][D]
    const __hip_bfloat16* __restrict__ wu,   // [17][F][D]
    const int* __restrict__ perm, const float* __restrict__ rowW,
    const int* __restrict__ tileE, const int* __restrict__ tileBase,
    __hip_bfloat16* __restrict__ H, int groupedStore)
{
  __shared__ __hip_bfloat16 sA[128 * 64];   // 16 KB
  __shared__ __hip_bfloat16 sG[64 * 64];    // 8 KB
  __shared__ __hip_bfloat16 sU[64 * 64];    // 8 KB
  __shared__ int   sTok[128];
  __shared__ float sW[128];

  const int tile = (blockIdx.x & 7) * (MAXTILES / 8) + (blockIdx.x >> 3);
  const int e = tileE[tile];
  if (e < 0) return;
  const int rbase = tileBase[tile];
  const int f0 = blockIdx.y * 64;
  const int tid = threadIdx.x;
  const int wid = tid >> 6, lane = tid & 63;
  const int wr = (wid >> 1) * 64, wc = (wid & 1) * 32;  // wave tile 64x32 (dual)
  const int rl = lane >> 3, cl = lane & 7;

  if (tid < 128) { const int r = rbase + tid; sTok[tid] = perm[r]; sW[tid] = rowW[r]; }
  __syncthreads();

  const __hip_bfloat16* wgE = wg + (size_t)e * FDIM * DDIM;
  const __hip_bfloat16* wuE = wu + (size_t)e * FDIM * DDIM;

  const char* pA[4]; const char* pG[2]; const char* pU[2]; int ldsA[4], ldsB[2];
#pragma unroll
  for (int i = 0; i < 4; i++) {
    const int row = 32 * wid + 8 * i + rl;
    const int sw = (cl ^ (row & 7)) << 3;
    int tk = sTok[row]; if (tk < 0) tk = 0;
    pA[i] = (const char*)(xb + (size_t)tk * DDIM + sw);
    ldsA[i] = (32 * wid + 8 * i) * 64;
  }
#pragma unroll
  for (int i = 0; i < 2; i++) {
    const int row = 16 * wid + 8 * i + rl;
    const int sw = (cl ^ (row & 7)) << 3;
    pG[i] = (const char*)(wgE + (size_t)(f0 + row) * DDIM + sw);
    pU[i] = (const char*)(wuE + (size_t)(f0 + row) * DDIM + sw);
    ldsB[i] = (16 * wid + 8 * i) * 64;
  }

  const f32x4 vzero = {0.f, 0.f, 0.f, 0.f};
  f32x4 accG[4][2], accU[4][2];
#pragma unroll
  for (int m = 0; m < 4; m++)
#pragma unroll
    for (int n = 0; n < 2; n++) { accG[m][n] = vzero; accU[m][n] = vzero; }

  for (int k0 = 0; k0 < DDIM; k0 += 64) {
    __syncthreads();
#pragma unroll
    for (int i = 0; i < 4; i++) gload_lds16(pA[i] + (size_t)k0 * 2, &sA[ldsA[i]]);
#pragma unroll
    for (int i = 0; i < 2; i++) {
      gload_lds16(pG[i] + (size_t)k0 * 2, &sG[ldsB[i]]);
      gload_lds16(pU[i] + (size_t)k0 * 2, &sU[ldsB[i]]);
    }
    __syncthreads();
#pragma unroll
    for (int kk = 0; kk < 2; kk++) {
      const int kch = kk * 4 + (lane >> 4);
      bf16x8 af[4], bg[2], bu[2];
#pragma unroll
      for (int m = 0; m < 4; m++) af[m] = frag_ld(sA, wr + m * 16 + (lane & 15), kch);
#pragma unroll
      for (int n = 0; n < 2; n++) {
        bg[n] = frag_ld(sG, wc + n * 16 + (lane & 15), kch);
        bu[n] = frag_ld(sU, wc + n * 16 + (lane & 15), kch);
      }
#pragma unroll
      for (int m = 0; m < 4; m++)
#pragma unroll
        for (int n = 0; n < 2; n++) {
          accG[m][n] = __builtin_amdgcn_mfma_f32_16x16x32_bf16(af[m], bg[n], accG[m][n], 0, 0, 0);
          accU[m][n] = __builtin_amdgcn_mfma_f32_16x16x32_bf16(af[m], bu[n], accU[m][n], 0, 0, 0);
        }
    }
  }
  const int lr = (lane >> 4) * 4, lc = lane & 15;
#pragma unroll
  for (int m = 0; m < 4; m++)
#pragma unroll
    for (int n = 0; n < 2; n++)
#pragma unroll
      for (int j = 0; j < 4; j++) {
        const int r = wr + m * 16 + lr + j;
        const int c = wc + n * 16 + lc;
        const int tok = sTok[r];
        if (tok >= 0) {
          const float g = accG[m][n][j], u = accU[m][n][j];
          const float h = (g / (1.0f + __expf(-g))) * u * sW[r];
          const size_t idx = groupedStore
              ? ((size_t)(rbase + r) * FDIM + f0 + c)
              : (((size_t)e * T_TOK + tok) * FDIM + f0 + c);
          H[idx] = __float2bfloat16(h);
        }
      }
}

// ---------------------------------------------------------------------------
// Stage B grouped: outp[row][d] = Hp[row][:] @ wd_t[e][d][:] (K=512), fp16 out.
// PROVEN round-10/12 codegen: bounds (256,4), VGPR 88, no spill.
__global__ __launch_bounds__(256, 4) void moe_stageB_grouped(
    const __hip_bfloat16* __restrict__ Hp,   // [MAXROWS][F]
    const __hip_bfloat16* __restrict__ wd,   // [17][D][F]
    const int* __restrict__ tileE, const int* __restrict__ tileBase,
    _Float16* __restrict__ outp)             // [MAXROWS][D] fp16
{
  __shared__ __hip_bfloat16 sA[128 * 64];
  __shared__ __hip_bfloat16 sB[128 * 64];

  const int tile = (blockIdx.x & 7) * (MAXTILES / 8) + (blockIdx.x >> 3);
  const int e = tileE[tile];
  if (e < 0) return;
  const int rbase = tileBase[tile];
  const int d0 = blockIdx.y * 128;
  const int tid = threadIdx.x, wid = tid >> 6, lane = tid & 63;
  const int wr = (wid >> 1) * 64, wc = (wid & 1) * 64;  // wave tile 64x64
  const int rl = lane >> 3, cl = lane & 7;

  const __hip_bfloat16* wdE = wd + (size_t)e * DDIM * FDIM;

  size_t offA[4], offB[4]; int ldsO[4];
#pragma unroll
  for (int i = 0; i < 4; i++) {
    const int row = 32 * wid + 8 * i + rl;
    const int sw = (cl ^ (row & 7)) << 3;
    offA[i] = (size_t)(rbase + row) * FDIM + sw;
    offB[i] = (size_t)(d0 + row) * FDIM + sw;
    ldsO[i] = (32 * wid + 8 * i) * 64;
  }

  const f32x4 vzero = {0.f, 0.f, 0.f, 0.f};
  f32x4 acc[4][4];
#pragma unroll
  for (int m = 0; m < 4; m++)
#pragma unroll
    for (int n = 0; n < 4; n++) acc[m][n] = vzero;

  for (int k0 = 0; k0 < FDIM; k0 += 64) {
    __syncthreads();
#pragma unroll
    for (int i = 0; i < 4; i++) {
      gload_lds16(Hp  + offA[i] + k0, &sA[ldsO[i]]);
      gload_lds16(wdE + offB[i] + k0, &sB[ldsO[i]]);
    }
    __syncthreads();
#pragma unroll
    for (int kk = 0; kk < 2; kk++) {
      const int kch = kk * 4 + (lane >> 4);
      bf16x8 af[4], bb[4];
#pragma unroll
      for (int m = 0; m < 4; m++) af[m] = frag_ld(sA, wr + m * 16 + (lane & 15), kch);
#pragma unroll
      for (int n = 0; n < 4; n++) bb[n] = frag_ld(sB, wc + n * 16 + (lane & 15), kch);
#pragma unroll
      for (int m = 0; m < 4; m++)
#pragma unroll
        for (int n = 0; n < 4; n++)
          acc[m][n] = __builtin_amdgcn_mfma_f32_16x16x32_bf16(af[m], bb[n], acc[m][n], 0, 0, 0);
    }
  }
  const int lr = (lane >> 4) * 4, lc = lane & 15;
#pragma unroll
  for (int m = 0; m < 4; m++)
#pragma unroll
    for (int n = 0; n < 4; n++)
#pragma unroll
      for (int j = 0; j < 4; j++)
        outp[(size_t)(rbase + wr + m * 16 + lr + j) * DDIM + d0 + wc + n * 16 + lc]
            = (_Float16)acc[m][n][j];
}

// Combine: out[t] = outp[sharedRow(t)] + sum_{s=0..7} outp[tok2row[t][s]]
__global__ __launch_bounds__(256) void moe_combine(
    const _Float16* __restrict__ outp, const int* __restrict__ tok2row,
    const int* __restrict__ padBase, float* __restrict__ out) {
  const int tid = threadIdx.x;  // 256; 256*f16x4 = 1024 = DDIM
  const int pb16 = padBase[16];
  const int tEnd = blockIdx.x * 8 + 8;
  for (int t = blockIdx.x * 8; t < tEnd; t++) {
    float4 a = {0.f, 0.f, 0.f, 0.f};
    {
      const f16x4 v = ((const f16x4*)(outp + (size_t)(pb16 + t) * DDIM))[tid];
      a.x += (float)v[0]; a.y += (float)v[1]; a.z += (float)v[2]; a.w += (float)v[3];
    }
#pragma unroll
    for (int s = 0; s < 8; s++) {
      const int r = tok2row[t * 8 + s];  // same addr across threads: broadcast
      const f16x4 v = ((const f16x4*)(outp + (size_t)r * DDIM))[tid];
      a.x += (float)v[0]; a.y += (float)v[1]; a.z += (float)v[2]; a.w += (float)v[3];
    }
    ((float4*)out)[(size_t)t * (DDIM / 4) + tid] = a;
  }
}

// ---------------------------------------------------------------------------
// Fallback dense stage B (round-6 path): K-split x3 over concat experts.
__global__ __launch_bounds__(256, 4) void moe_stageB_split(
    const __hip_bfloat16* __restrict__ H,    // [17][T][F] dense
    const __hip_bfloat16* __restrict__ wd,   // [17][D][F]
    float* __restrict__ out, float* __restrict__ p0, float* __restrict__ p1)
{
  __shared__ __hip_bfloat16 sA[128 * 64];
  __shared__ __hip_bfloat16 sB[128 * 64];
  const int id = blockIdx.x;
  const int xcd = id & 7, slot = id >> 3;
  const int t0 = (xcd * 4 + (slot & 3)) * 128;
  const int d0 = (slot >> 2) * 128;
  const int tid = threadIdx.x, wid = tid >> 6, lane = tid & 63;
  const int wr = (wid >> 1) * 64, wc = (wid & 1) * 64;
  const int rl = lane >> 3, cl = lane & 7;
  size_t offA[4], offB[4]; int ldsO[4];
#pragma unroll
  for (int i = 0; i < 4; i++) {
    const int row = 32 * wid + 8 * i + rl;
    const int sw = (cl ^ (row & 7)) << 3;
    offA[i] = (size_t)(t0 + row) * FDIM + sw;
    offB[i] = (size_t)(d0 + row) * FDIM + sw;
    ldsO[i] = (32 * wid + 8 * i) * 64;
  }
  const f32x4 vzero = {0.f, 0.f, 0.f, 0.f};
  f32x4 acc[4][4];
#pragma unroll
  for (int m = 0; m < 4; m++)
#pragma unroll
    for (int n = 0; n < 4; n++) acc[m][n] = vzero;
  const int NKS = NE17 * FDIM / 64;
  const int split = blockIdx.y;
  const int ks0 = (split * NKS) / 3, ks1 = ((split + 1) * NKS) / 3;
  for (int ks = ks0; ks < ks1; ks++) {
    const int k0 = ks * 64;
    const int ee = k0 >> 9, ff = k0 & 511;
    const size_t sOffA = (size_t)ee * T_TOK * FDIM + ff;
    const size_t sOffB = (size_t)ee * DDIM * FDIM + ff;
    __syncthreads();
#pragma unroll
    for (int i = 0; i < 4; i++) {
      gload_lds16(H  + sOffA + offA[i], &sA[ldsO[i]]);
      gload_lds16(wd + sOffB + offB[i], &sB[ldsO[i]]);
    }
    __syncthreads();
#pragma unroll
    for (int kk = 0; kk < 2; kk++) {
      const int kch = kk * 4 + (lane >> 4);
      bf16x8 af[4], bb[4];
#pragma unroll
      for (int m = 0; m < 4; m++) af[m] = frag_ld(sA, wr + m * 16 + (lane & 15), kch);
#pragma unroll
      for (int n = 0; n < 4; n++) bb[n] = frag_ld(sB, wc + n * 16 + (lane & 15), kch);
#pragma unroll
      for (int m = 0; m < 4; m++)
#pragma unroll
        for (int n = 0; n < 4; n++)
          acc[m][n] = __builtin_amdgcn_mfma_f32_16x16x32_bf16(af[m], bb[n], acc[m][n], 0, 0, 0);
    }
  }
  float* dst = (split == 0) ? p0 : (split == 1) ? p1 : out;
  const int lr = (lane >> 4) * 4, lc = lane & 15;
#pragma unroll
  for (int m = 0; m < 4; m++)
#pragma unroll
    for (int n = 0; n < 4; n++)
#pragma unroll
      for (int j = 0; j < 4; j++)
        dst[(size_t)(t0 + wr + m * 16 + lr + j) * DDIM + d0 + wc + n * 16 + lc] = acc[m][n][j];
}

__global__ void add_partial(float* __restrict__ out, const float* __restrict__ p0,
                            const float* __restrict__ p1, int n4) {
  int i = blockIdx.x * blockDim.x + threadIdx.x;
  if (i >= n4) return;
  float4 a = ((const float4*)out)[i];
  float4 b = ((const float4*)p0)[i];
  float4 c = ((const float4*)p1)[i];
  a.x += b.x + c.x; a.y += b.y + c.y; a.z += b.z + c.z; a.w += b.w + c.w;
  ((float4*)out)[i] = a;
}

// ---------------------------------------------------------------------------
extern "C" void kernel_launch(void* const* d_in, const int* in_sizes, int n_in,
                              void* d_out, int out_size, void* d_ws, size_t ws_size,
                              hipStream_t stream) {
  const float* x  = (const float*)d_in[0];
  const float* rw = (const float*)d_in[1];
  const float* gw = (const float*)d_in[2];
  const float* uw = (const float*)d_in[3];
  const float* dw = (const float*)d_in[4];
  const float* sg = (const float*)d_in[5];
  const float* su = (const float*)d_in[6];
  const float* sd = (const float*)d_in[7];
  float* out = (float*)d_out;

  char* ws = (char*)d_ws;
  size_t off = 0;
  __hip_bfloat16* xb = (__hip_bfloat16*)(ws + off); off += (size_t)T_TOK * DDIM * 2;
  __hip_bfloat16* wg = (__hip_bfloat16*)(ws + off); off += (size_t)NE17 * FDIM * DDIM * 2;
  __hip_bfloat16* wu = (__hip_bfloat16*)(ws + off);
  const size_t wu_off = off;                         off += (size_t)NE17 * FDIM * DDIM * 2;
  __hip_bfloat16* wd = (__hip_bfloat16*)(ws + off);  off += (size_t)NE17 * DDIM * FDIM * 2;
  __hip_bfloat16* H  = (__hip_bfloat16*)(ws + off);
  const size_t H_bytes = (size_t)NE17 * T_TOK * FDIM * 2; off += H_bytes;
  float* cwT     = (float*)(ws + off); off += (size_t)NEXP * T_TOK * 4;
  int*   padBase = (int*)(ws + off);   off += 32 * 4;
  int*   tileE   = (int*)(ws + off);   off += MAXTILES * 4;
  int*   tileBase= (int*)(ws + off);   off += MAXTILES * 4;
  int*   perm    = (int*)(ws + off);   off += MAXROWS * 4;
  float* rowW    = (float*)(ws + off); off += MAXROWS * 4;
  unsigned* selMask = (unsigned*)(ws + off); off += (size_t)T_TOK * 4;
  int*   tok2row = (int*)(ws + off);   off += (size_t)T_TOK * 8 * 4;
  // grouped-mode extra: fp16 outp[MAXROWS][D] appended at the end (83.9 MB)
  const size_t outp_bytes = (size_t)MAXROWS * DDIM * 2;
  _Float16* outp = (_Float16*)(ws + off);
  const bool grouped = (ws_size >= off + outp_bytes);
  // fallback partials alias dead regions (xb+wg, wu)
  float* p0 = (float*)ws;
  float* p1 = (float*)(ws + wu_off);
  (void)in_sizes; (void)n_in; (void)out_size;

  if (!grouped) hipMemsetAsync(H, 0, H_bytes, stream);  // dense H needs zeros

  // one prep launch: weight transposes (z<34) + x-convert/router (z>=34)
  moe_prep<<<dim3(8, 16, 2 * NE17 + 8), 256, 0, stream>>>(
      gw, sg, uw, su, dw, sd, wg, wu, wd, x, rw, xb, cwT, selMask);
  moe_group<<<NE17, 256, 0, stream>>>(cwT, selMask, padBase, tileE, tileBase,
                                      perm, rowW, tok2row);

  moe_stageA_grouped<<<dim3(MAXTILES, FDIM / 64), 256, 0, stream>>>(
      xb, wg, wu, perm, rowW, tileE, tileBase, H, grouped ? 1 : 0);

  if (grouped) {
    moe_stageB_grouped<<<dim3(MAXTILES, DDIM / 128), 256, 0, stream>>>(
        H, wd, tileE, tileBase, outp);
    moe_combine<<<T_TOK / 8, 256, 0, stream>>>(outp, tok2row, padBase, out);
  } else {
    moe_stageB_split<<<dim3(256, 3), 256, 0, stream>>>(H, wd, out, p0, p1);
    add_partial<<<(T_TOK * DDIM / 4 + 255) / 256, 256, 0, stream>>>(out, p0, p1, T_TOK * DDIM / 4);
  }
}